// Round 1
// baseline (577.577 us; speedup 1.0000x reference)
//
#include <hip/hip_runtime.h>
#include <cstdint>

typedef __bf16 bf16;
typedef __bf16 bf16x8 __attribute__((ext_vector_type(8)));
typedef float f32x4 __attribute__((ext_vector_type(4)));

#define DEVI __device__ __forceinline__

DEVI float bits2f(uint32_t u){ union{uint32_t u;float f;}x; x.u=u; return x.f; }

DEVI void gload_lds16(const void* g, void* l){
  __builtin_amdgcn_global_load_lds(
    (const __attribute__((address_space(1))) uint32_t*)g,
    (__attribute__((address_space(3))) uint32_t*)l, 16, 0, 0);
}

// ---------- cast fp32 -> bf16, 8 elems/thread ----------
__global__ __launch_bounds__(256) void k_cast(const float* __restrict__ x, bf16* __restrict__ o, int n){
  int i = (blockIdx.x*256 + threadIdx.x)*8;
  if (i >= n) return;
  float4 a = *(const float4*)(x+i);
  float4 b = *(const float4*)(x+i+4);
  union { bf16 h[8]; uint4 u; } r;
  r.h[0]=(bf16)a.x; r.h[1]=(bf16)a.y; r.h[2]=(bf16)a.z; r.h[3]=(bf16)a.w;
  r.h[4]=(bf16)b.x; r.h[5]=(bf16)b.y; r.h[6]=(bf16)b.z; r.h[7]=(bf16)b.w;
  *(uint4*)(o+i) = r.u;
}

// ---------- transpose + cast: WT[c][r] = W[r][c] ----------
__global__ __launch_bounds__(256) void k_transpose(const float* __restrict__ W, bf16* __restrict__ WT, int R, int Ccols){
  __shared__ float tile[32][33];
  int bc = blockIdx.x*32, br = blockIdx.y*32;
  int lc = threadIdx.x & 31, lr = threadIdx.x >> 5; // lr 0..7
  #pragma unroll
  for (int i=0;i<4;i++){
    int r = lr + i*8;
    tile[r][lc] = W[(size_t)(br+r)*Ccols + bc + lc];
  }
  __syncthreads();
  #pragma unroll
  for (int i=0;i<4;i++){
    int r = lr + i*8;
    WT[(size_t)(bc+r)*R + br + lc] = (bf16)tile[lc][r];
  }
}

// ---------- 128x128 tile bf16 GEMM (m97 structure), B given transposed [N][K] ----------
// EPI=0: C[m][n] = bf16(acc)
// EPI=1: C[m][n] = bf16(acc + bias[n] + resid[m][n])   (resid fp32, stride N)
template<int EPI>
__global__ __launch_bounds__(256) void k_gemm(
    const bf16* __restrict__ A, const bf16* __restrict__ BT, bf16* __restrict__ C,
    int M, int N, int K,
    const float* __restrict__ bias, const float* __restrict__ resid)
{
  __shared__ __align__(16) bf16 sA[128*64];
  __shared__ __align__(16) bf16 sB[128*64];
  const int t = threadIdx.x, w = t>>6, l = t&63;
  const int bm = blockIdx.y*128, bn = blockIdx.x*128;
  const int wr = (w>>1)*64, wc = (w&1)*64;
  f32x4 acc[4][4] = {};
  // staging: chunk c = w*4+i covers rows c*8 .. c*8+7 (8 rows x 128B = 1KB)
  // swizzled source: LDS[row][slot] = G[row][slot ^ (row&7)], slot = lane&7, row&7 = lane>>3
  const int srow = l>>3;                      // row within chunk (0..7) == row&7
  const int scol = ((l&7) ^ (l>>3))*8;        // source col in elements
  const int nk = K>>6;
  for (int kt=0; kt<nk; ++kt) {
    const int k0 = kt*64;
    #pragma unroll
    for (int i=0;i<4;++i){
      int c = w*4+i;
      int row = c*8 + srow;
      gload_lds16(A  + (size_t)(bm+row)*K + k0 + scol, (char*)sA + c*1024);
      gload_lds16(BT + (size_t)(bn+row)*K + k0 + scol, (char*)sB + c*1024);
    }
    __syncthreads();
    #pragma unroll
    for (int kk=0; kk<64; kk+=32) {
      bf16x8 af[4], bfr[4];
      const int xr = ((kk + 8*(l>>4))*2) ^ ((l&7)<<4);  // swizzled byte offset within row
      #pragma unroll
      for (int mf=0;mf<4;++mf){
        int row = wr + mf*16 + (l&15);        // row&7 == l&7
        af[mf] = *(const bf16x8*)((const char*)sA + row*128 + xr);
      }
      #pragma unroll
      for (int nf=0;nf<4;++nf){
        int row = wc + nf*16 + (l&15);
        bfr[nf] = *(const bf16x8*)((const char*)sB + row*128 + xr);
      }
      #pragma unroll
      for (int mf=0;mf<4;++mf)
        #pragma unroll
        for (int nf=0;nf<4;++nf)
          acc[mf][nf] = __builtin_amdgcn_mfma_f32_16x16x32_bf16(af[mf], bfr[nf], acc[mf][nf], 0,0,0);
    }
    __syncthreads();
  }
  #pragma unroll
  for (int mf=0;mf<4;++mf){
    #pragma unroll
    for (int nf=0;nf<4;++nf){
      #pragma unroll
      for (int r=0;r<4;++r){
        int row = bm + wr + mf*16 + (l>>4)*4 + r;
        int col = bn + wc + nf*16 + (l&15);
        float v = acc[mf][nf][r];
        if (EPI==1) v += bias[col] + resid[(size_t)row*N + col];
        C[(size_t)row*N + col] = (bf16)v;
      }
    }
  }
}

// ---------- channel scores: Sp[ks][bg][d][e] = sum_{n in ks-chunk} k[n][d]*v[n][e] ----------
__global__ __launch_bounds__(256) void k_scores(const bf16* __restrict__ qkv, float* __restrict__ Sp){
  const int ks = blockIdx.x, bg = blockIdx.y;
  const int b = bg>>4, g = bg&15;
  __shared__ __align__(16) bf16 kT[64][64];
  __shared__ __align__(16) bf16 vT[64][64];
  const int t = threadIdx.x;
  const int d0 = (t&15)*4, e0 = (t>>4)*4;
  float acc[4][4] = {};
  const bf16* base = qkv + (size_t)(b*4096 + ks*512)*3072 + g*64;
  for (int sub=0; sub<8; ++sub){
    __syncthreads();
    for (int idx=t; idx<512; idx+=256){
      int row = idx>>3, c8 = (idx&7)*8;
      const bf16* s = base + (size_t)(sub*64+row)*3072 + 1024 + c8;
      *(uint4*)&kT[row][c8] = *(const uint4*)s;
      *(uint4*)&vT[row][c8] = *(const uint4*)(s + 1024);
    }
    __syncthreads();
    #pragma unroll 4
    for (int n=0;n<64;++n){
      uint2 ku = *(const uint2*)&kT[n][d0];
      uint2 vu = *(const uint2*)&vT[n][e0];
      float kf[4] = { bits2f(ku.x<<16), bits2f(ku.x&0xffff0000u), bits2f(ku.y<<16), bits2f(ku.y&0xffff0000u) };
      float vf[4] = { bits2f(vu.x<<16), bits2f(vu.x&0xffff0000u), bits2f(vu.y<<16), bits2f(vu.y&0xffff0000u) };
      #pragma unroll
      for (int i=0;i<4;++i)
        #pragma unroll
        for (int j=0;j<4;++j)
          acc[i][j] += kf[i]*vf[j];
    }
  }
  float* o = Sp + ((size_t)ks*128 + bg)*4096;
  #pragma unroll
  for (int i=0;i<4;++i)
    #pragma unroll
    for (int j=0;j<4;++j)
      o[(d0+i)*64 + e0+j] = acc[i][j];
}

// ---------- reduce partials, scale, softmax over e, write bf16 P ----------
__global__ __launch_bounds__(256) void k_softmax(const float* __restrict__ Sp, bf16* __restrict__ P){
  const int bg = blockIdx.x;
  __shared__ float S[64][64];
  const int t = threadIdx.x;
  for (int idx=t; idx<4096; idx+=256){
    float s = 0;
    #pragma unroll
    for (int ks=0;ks<8;++ks) s += Sp[((size_t)ks*128+bg)*4096 + idx];
    S[idx>>6][idx&63] = s * 0.125f;  // scale = hd^-0.5
  }
  __syncthreads();
  const int row = t>>2, qd = t&3;
  float m = -3.4e38f;
  #pragma unroll
  for (int j=0;j<16;++j) m = fmaxf(m, S[row][qd*16+j]);
  m = fmaxf(m, __shfl_xor(m,1));
  m = fmaxf(m, __shfl_xor(m,2));
  float e[16]; float sum = 0.f;
  #pragma unroll
  for (int j=0;j<16;++j){ e[j] = expf(S[row][qd*16+j]-m); sum += e[j]; }
  sum += __shfl_xor(sum,1);
  sum += __shfl_xor(sum,2);
  float inv = 1.0f/sum;
  #pragma unroll
  for (int j=0;j<16;++j) P[(size_t)bg*4096 + row*64 + qd*16 + j] = (bf16)(e[j]*inv);
}

// ---------- out2[n][d] = sum_e P[d][e] * q[n][e], per (b,g); MFMA ----------
__global__ __launch_bounds__(256) void k_apply(const bf16* __restrict__ qkv, const bf16* __restrict__ P, bf16* __restrict__ outA){
  const int bg = blockIdx.y, b = bg>>4, g = bg&15;
  const int m0 = blockIdx.x*128;
  __shared__ __align__(16) bf16 Pl[64][72];   // pad 64->72 elems (144B rows, 16B-aligned)
  const int t = threadIdx.x, w = t>>6, l = t&63;
  for (int idx=t; idx<1024; idx+=256){
    int r = idx>>4, c4 = (idx&15)*4;
    *(uint2*)&Pl[r][c4] = *(const uint2*)&P[(size_t)bg*4096 + r*64 + c4];
  }
  __syncthreads();
  f32x4 acc[2][4] = {};
  const bf16* qb = qkv + (size_t)(b*4096 + m0 + w*32)*3072 + g*64;
  #pragma unroll
  for (int kk=0; kk<64; kk+=32){
    bf16x8 af[2], pf[4];
    #pragma unroll
    for (int mf=0;mf<2;++mf)
      af[mf] = *(const bf16x8*)(qb + (size_t)(mf*16 + (l&15))*3072 + kk + 8*(l>>4));
    #pragma unroll
    for (int nf=0;nf<4;++nf)
      pf[nf] = *(const bf16x8*)&Pl[nf*16 + (l&15)][kk + 8*(l>>4)];
    #pragma unroll
    for (int mf=0;mf<2;++mf)
      #pragma unroll
      for (int nf=0;nf<4;++nf)
        acc[mf][nf] = __builtin_amdgcn_mfma_f32_16x16x32_bf16(af[mf], pf[nf], acc[mf][nf], 0,0,0);
  }
  #pragma unroll
  for (int mf=0;mf<2;++mf)
    #pragma unroll
    for (int nf=0;nf<4;++nf)
      #pragma unroll
      for (int r=0;r<4;++r){
        int rown = m0 + w*32 + mf*16 + (l>>4)*4 + r;
        int col = g*64 + nf*16 + (l&15);
        outA[(size_t)(b*4096 + rown)*1024 + col] = (bf16)acc[mf][nf][r];
      }
}

// ---------- LayerNorm: wave per row of 1024 ----------
__global__ __launch_bounds__(256) void k_ln(const bf16* __restrict__ h, const float* __restrict__ gamma,
                                            const float* __restrict__ beta, float* __restrict__ y){
  const int w = threadIdx.x>>6, l = threadIdx.x&63;
  const size_t row = (size_t)blockIdx.x*4 + w;
  const bf16* hr = h + row*1024 + l*16;
  uint4 p0 = *(const uint4*)hr;
  uint4 p1 = *(const uint4*)(hr+8);
  float v[16];
  const uint32_t* pw = (const uint32_t*)&p0;
  #pragma unroll
  for (int i=0;i<4;++i){ v[2*i] = bits2f(pw[i]<<16); v[2*i+1] = bits2f(pw[i]&0xffff0000u); }
  const uint32_t* pw1 = (const uint32_t*)&p1;
  #pragma unroll
  for (int i=0;i<4;++i){ v[8+2*i] = bits2f(pw1[i]<<16); v[8+2*i+1] = bits2f(pw1[i]&0xffff0000u); }
  float s=0.f, s2=0.f;
  #pragma unroll
  for (int i=0;i<16;++i){ s+=v[i]; s2+=v[i]*v[i]; }
  #pragma unroll
  for (int off=1; off<64; off<<=1){ s += __shfl_xor(s,off); s2 += __shfl_xor(s2,off); }
  float mu = s*(1.0f/1024.0f);
  float var = s2*(1.0f/1024.0f) - mu*mu;
  float rinv = rsqrtf(var + 1e-5f);
  const float* gp = gamma + l*16; const float* bp = beta + l*16;
  float o[16];
  #pragma unroll
  for (int i=0;i<16;++i) o[i] = gp[i]*(v[i]-mu)*rinv + bp[i];
  float* yr = y + row*1024 + l*16;
  #pragma unroll
  for (int i=0;i<4;++i) ((float4*)yr)[i] = *(float4*)&o[4*i];
}

extern "C" void kernel_launch(void* const* d_in, const int* in_sizes, int n_in,
                              void* d_out, int out_size, void* d_ws, size_t ws_size,
                              hipStream_t stream){
  const float* x     = (const float*)d_in[0];
  const float* Wqkv  = (const float*)d_in[1];
  const float* Wproj = (const float*)d_in[2];
  const float* bproj = (const float*)d_in[3];
  const float* gamma = (const float*)d_in[4];
  const float* beta  = (const float*)d_in[5];
  float* y = (float*)d_out;

  char* ws = (char*)d_ws;
  size_t off = 0;
  auto alloc = [&](size_t bytes)->void*{ void* p = ws + off; off += (bytes + 255) & ~(size_t)255; return p; };
  bf16*  qkv    = (bf16*) alloc((size_t)32768*3072*2);  // 201.3 MB
  bf16*  xb     = (bf16*) alloc((size_t)32768*1024*2);  // 67.1 MB (x_bf16, then out_attn)
  bf16*  WqkvT  = (bf16*) alloc((size_t)3072*1024*2);
  bf16*  WprojT = (bf16*) alloc((size_t)1024*1024*2);
  float* Sp     = (float*)alloc((size_t)8*128*4096*4);  // 16.8 MB
  bf16*  P      = (bf16*) alloc((size_t)128*4096*2);
  bf16*  h      = qkv;  // qkv dead after k_apply; reuse for h

  k_cast<<<16384,256,0,stream>>>(x, xb, 33554432);
  k_transpose<<<dim3(96,32),256,0,stream>>>(Wqkv, WqkvT, 1024, 3072);
  k_transpose<<<dim3(32,32),256,0,stream>>>(Wproj, WprojT, 1024, 1024);
  // qkv = x @ Wqkv   [32768 x 3072]
  k_gemm<0><<<dim3(24,256),256,0,stream>>>(xb, WqkvT, qkv, 32768, 3072, 1024, nullptr, nullptr);
  // S partials (split-K over n)
  k_scores<<<dim3(8,128),256,0,stream>>>(qkv, Sp);
  k_softmax<<<128,256,0,stream>>>(Sp, P);
  // out_attn = q @ P^T  -> xb
  k_apply<<<dim3(32,128),256,0,stream>>>(qkv, P, xb);
  // h = out_attn @ Wproj + bproj + x   [32768 x 1024] bf16
  k_gemm<1><<<dim3(8,256),256,0,stream>>>(xb, WprojT, h, 32768, 1024, 1024, bproj, x);
  k_ln<<<8192,256,0,stream>>>(h, gamma, beta, y);
}

// Round 2
// 525.614 us; speedup vs baseline: 1.0989x; 1.0989x over previous
//
#include <hip/hip_runtime.h>
#include <cstdint>

typedef __bf16 bf16;
typedef __bf16 bf16x8 __attribute__((ext_vector_type(8)));
typedef float f32x4 __attribute__((ext_vector_type(4)));

#define DEVI __device__ __forceinline__

DEVI float bits2f(uint32_t u){ union{uint32_t u;float f;}x; x.u=u; return x.f; }

DEVI void gload_lds16(const void* g, void* l){
  __builtin_amdgcn_global_load_lds(
    (const __attribute__((address_space(1))) uint32_t*)g,
    (__attribute__((address_space(3))) uint32_t*)l, 16, 0, 0);
}

// ---------- cast fp32 -> bf16, 8 elems/thread ----------
__global__ __launch_bounds__(256) void k_cast(const float* __restrict__ x, bf16* __restrict__ o, int n){
  int i = (blockIdx.x*256 + threadIdx.x)*8;
  if (i >= n) return;
  float4 a = *(const float4*)(x+i);
  float4 b = *(const float4*)(x+i+4);
  union { bf16 h[8]; uint4 u; } r;
  r.h[0]=(bf16)a.x; r.h[1]=(bf16)a.y; r.h[2]=(bf16)a.z; r.h[3]=(bf16)a.w;
  r.h[4]=(bf16)b.x; r.h[5]=(bf16)b.y; r.h[6]=(bf16)b.z; r.h[7]=(bf16)b.w;
  *(uint4*)(o+i) = r.u;
}

// ---------- transpose + cast: WT[c][r] = W[r][c] ----------
__global__ __launch_bounds__(256) void k_transpose(const float* __restrict__ W, bf16* __restrict__ WT, int R, int Ccols){
  __shared__ float tile[32][33];
  int bc = blockIdx.x*32, br = blockIdx.y*32;
  int lc = threadIdx.x & 31, lr = threadIdx.x >> 5; // lr 0..7
  #pragma unroll
  for (int i=0;i<4;i++){
    int r = lr + i*8;
    tile[r][lc] = W[(size_t)(br+r)*Ccols + bc + lc];
  }
  __syncthreads();
  #pragma unroll
  for (int i=0;i<4;i++){
    int r = lr + i*8;
    WT[(size_t)(bc+r)*R + br + lc] = (bf16)tile[lc][r];
  }
}

// =====================================================================
// 256x256-tile, BK=64, 8-wave (2M x 4N), 8-phase-family GEMM with
// counted vmcnt (T3+T4), st-swizzled LDS (T2), setprio (T5), XCD swizzle (T1).
// B given transposed: BT[n][k]. C = A * BT^T.
// Staging ledger (per K-tile T, 4 phases):
//   p0: ds_read B-frags(8)+A q0(4); stage A(T+1) issues 0,2 -> slot^1
//   p1: ds_read A q1;               stage A(T+1) issues 1,3
//   p2: ds_read A q2;               stage B(T+2) issues 0,1 -> this slot (B(T) was
//                                   fully consumed into regs at p0)
//   p3: ds_read A q3;               stage B(T+2) issues 2,3; vmcnt(4) (leaves the
//                                   4 B(T+2) loads in flight; confirms A(T+1),B(T+1))
// Prologue stages A(0),B(0),B(1) then vmcnt(4).
// =====================================================================
template<int EPI>
__global__ __launch_bounds__(512, 2) void k_gemm(
    const bf16* __restrict__ A, const bf16* __restrict__ BT, bf16* __restrict__ C,
    int M, int N, int K,
    const float* __restrict__ bias, const float* __restrict__ resid)
{
  __shared__ __align__(16) bf16 lds[2][2][256*64];   // [slot][0=A,1=B] = 128 KiB
  bf16* bA0 = &lds[0][0][0]; bf16* bB0 = &lds[0][1][0];
  bf16* bA1 = &lds[1][0][0]; bf16* bB1 = &lds[1][1][0];

  const int t = threadIdx.x, w = t>>6, l = t&63;
  const int wm = w>>2, wn = w&3;

  // XCD-aware bijective block swizzle (m204 variant)
  const int nwg = gridDim.x * gridDim.y;
  const int orig = blockIdx.y * gridDim.x + blockIdx.x;
  const int q = nwg >> 3, r = nwg & 7;
  const int xcd = orig & 7, loc = orig >> 3;
  const int swz = (xcd < r ? xcd*(q+1) : r*(q+1) + (xcd-r)*q) + loc;
  const int bx = swz % gridDim.x, by = swz / gridDim.x;
  const int bm = by*256, bn = bx*256;

  // swizzled read column offsets (bytes within a 128B row), kk = 0,1
  const int co0 = (16*(l>>4)) ^ ((l&7)<<4);
  const int co1 = (64 + 16*(l>>4)) ^ ((l&7)<<4);

  // stage one 64-row issue (8KB: 512 thr x 16B). LDS dest linear; source col
  // pre-swizzled so read-XOR ((row&7)<<4) recovers linear data (rule #21).
  auto stage = [&](const bf16* G, int grow, bf16* Ldst, int j, int k0){
    int row = j*64 + w*8 + (l>>3);
    int col = 8*((l&7) ^ (l>>3));
    gload_lds16(G + (size_t)(grow + row)*K + k0 + col,
                Ldst + (j*64 + w*8)*64);
  };

  f32x4 acc[8][4] = {};
  const int NT = K >> 6;

  // ---- prologue ----
  #pragma unroll
  for (int j=0;j<4;++j) stage(A, bm, bA0, j, 0);
  #pragma unroll
  for (int j=0;j<4;++j) stage(BT, bn, bB0, j, 0);
  __builtin_amdgcn_sched_barrier(0);
  if (NT > 1){
    #pragma unroll
    for (int j=0;j<4;++j) stage(BT, bn, bB1, j, 64);
    asm volatile("s_waitcnt vmcnt(4)" ::: "memory");
  } else {
    asm volatile("s_waitcnt vmcnt(0)" ::: "memory");
  }
  asm volatile("s_barrier" ::: "memory");

#define GEMM_PHASE(P, STAGES, TAILWAIT) {                                       \
    bf16x8 aa[2][2];                                                            \
    const int r0 = wm*128 + P*32 + (l&15);                                      \
    aa[0][0] = *(const bf16x8*)((const char*)sA + (r0   )*128 + co0);           \
    aa[0][1] = *(const bf16x8*)((const char*)sA + (r0   )*128 + co1);           \
    aa[1][0] = *(const bf16x8*)((const char*)sA + (r0+16)*128 + co0);           \
    aa[1][1] = *(const bf16x8*)((const char*)sA + (r0+16)*128 + co1);           \
    STAGES;                                                                     \
    asm volatile("s_barrier" ::: "memory");                                     \
    asm volatile("s_waitcnt lgkmcnt(0)" ::: "memory");                          \
    __builtin_amdgcn_sched_barrier(0);                                          \
    __builtin_amdgcn_s_setprio(1);                                              \
    _Pragma("unroll")                                                           \
    for (int kk=0;kk<2;++kk)                                                    \
      _Pragma("unroll")                                                         \
      for (int i=0;i<2;++i)                                                     \
        _Pragma("unroll")                                                       \
        for (int nf=0;nf<4;++nf)                                                \
          acc[2*P+i][nf] = __builtin_amdgcn_mfma_f32_16x16x32_bf16(             \
              aa[i][kk], bfr[nf][kk], acc[2*P+i][nf], 0,0,0);                   \
    __builtin_amdgcn_s_setprio(0);                                              \
    TAILWAIT;                                                                   \
    asm volatile("s_barrier" ::: "memory");                                     \
  }

  for (int T = 0; T < NT; ++T){
    bf16* sA  = (T&1) ? bA1 : bA0;
    bf16* sB  = (T&1) ? bB1 : bB0;
    bf16* sAn = (T&1) ? bA0 : bA1;   // A(T+1) destination
    const int kA = (T+1)<<6, kB = (T+2)<<6;
    const bool stA = (T+1) < NT, stB = (T+2) < NT;

    // B fragments for the whole K-tile, register-cached (8 x ds_read_b128)
    bf16x8 bfr[4][2];
    const int rb = wn*64 + (l&15);
    #pragma unroll
    for (int nf=0;nf<4;++nf){
      bfr[nf][0] = *(const bf16x8*)((const char*)sB + (rb+nf*16)*128 + co0);
      bfr[nf][1] = *(const bf16x8*)((const char*)sB + (rb+nf*16)*128 + co1);
    }

    GEMM_PHASE(0, { if (stA){ stage(A, bm, sAn, 0, kA); stage(A, bm, sAn, 2, kA); } }, {});
    GEMM_PHASE(1, { if (stA){ stage(A, bm, sAn, 1, kA); stage(A, bm, sAn, 3, kA); } }, {});
    GEMM_PHASE(2, { if (stB){ stage(BT, bn, sB, 0, kB); stage(BT, bn, sB, 1, kB); } }, {});
    GEMM_PHASE(3, { if (stB){ stage(BT, bn, sB, 2, kB); stage(BT, bn, sB, 3, kB); } },
               { if (stB) asm volatile("s_waitcnt vmcnt(4)" ::: "memory");
                 else     asm volatile("s_waitcnt vmcnt(0)" ::: "memory"); });
  }
#undef GEMM_PHASE

  // ---- epilogue ----
  #pragma unroll
  for (int mf=0; mf<8; ++mf){
    #pragma unroll
    for (int nf=0; nf<4; ++nf){
      #pragma unroll
      for (int r2=0; r2<4; ++r2){
        int row = bm + wm*128 + mf*16 + (l>>4)*4 + r2;
        int col = bn + wn*64 + nf*16 + (l&15);
        float v = acc[mf][nf][r2];
        if (EPI==1) v += bias[col] + resid[(size_t)row*N + col];
        C[(size_t)row*N + col] = (bf16)v;
      }
    }
  }
}

// ---------- channel scores: Sp[ks][bg][d][e] = sum_{n in ks-chunk} k[n][d]*v[n][e] ----------
__global__ __launch_bounds__(256) void k_scores(const bf16* __restrict__ qkv, float* __restrict__ Sp){
  const int ks = blockIdx.x, bg = blockIdx.y;
  const int b = bg>>4, g = bg&15;
  __shared__ __align__(16) bf16 kT[64][64];
  __shared__ __align__(16) bf16 vT[64][64];
  const int t = threadIdx.x;
  const int d0 = (t&15)*4, e0 = (t>>4)*4;
  float acc[4][4] = {};
  const bf16* base = qkv + (size_t)(b*4096 + ks*512)*3072 + g*64;
  for (int sub=0; sub<8; ++sub){
    __syncthreads();
    for (int idx=t; idx<512; idx+=256){
      int row = idx>>3, c8 = (idx&7)*8;
      const bf16* s = base + (size_t)(sub*64+row)*3072 + 1024 + c8;
      *(uint4*)&kT[row][c8] = *(const uint4*)s;
      *(uint4*)&vT[row][c8] = *(const uint4*)(s + 1024);
    }
    __syncthreads();
    #pragma unroll 4
    for (int n=0;n<64;++n){
      uint2 ku = *(const uint2*)&kT[n][d0];
      uint2 vu = *(const uint2*)&vT[n][e0];
      float kf[4] = { bits2f(ku.x<<16), bits2f(ku.x&0xffff0000u), bits2f(ku.y<<16), bits2f(ku.y&0xffff0000u) };
      float vf[4] = { bits2f(vu.x<<16), bits2f(vu.x&0xffff0000u), bits2f(vu.y<<16), bits2f(vu.y&0xffff0000u) };
      #pragma unroll
      for (int i=0;i<4;++i)
        #pragma unroll
        for (int j=0;j<4;++j)
          acc[i][j] += kf[i]*vf[j];
    }
  }
  float* o = Sp + ((size_t)ks*128 + bg)*4096;
  #pragma unroll
  for (int i=0;i<4;++i)
    #pragma unroll
    for (int j=0;j<4;++j)
      o[(d0+i)*64 + e0+j] = acc[i][j];
}

// ---------- reduce partials, scale, softmax over e, write bf16 P ----------
__global__ __launch_bounds__(256) void k_softmax(const float* __restrict__ Sp, bf16* __restrict__ P){
  const int bg = blockIdx.x;
  __shared__ float S[64][64];
  const int t = threadIdx.x;
  for (int idx=t; idx<4096; idx+=256){
    float s = 0;
    #pragma unroll
    for (int ks=0;ks<8;++ks) s += Sp[((size_t)ks*128+bg)*4096 + idx];
    S[idx>>6][idx&63] = s * 0.125f;  // scale = hd^-0.5
  }
  __syncthreads();
  const int row = t>>2, qd = t&3;
  float m = -3.4e38f;
  #pragma unroll
  for (int j=0;j<16;++j) m = fmaxf(m, S[row][qd*16+j]);
  m = fmaxf(m, __shfl_xor(m,1));
  m = fmaxf(m, __shfl_xor(m,2));
  float e[16]; float sum = 0.f;
  #pragma unroll
  for (int j=0;j<16;++j){ e[j] = expf(S[row][qd*16+j]-m); sum += e[j]; }
  sum += __shfl_xor(sum,1);
  sum += __shfl_xor(sum,2);
  float inv = 1.0f/sum;
  #pragma unroll
  for (int j=0;j<16;++j) P[(size_t)bg*4096 + row*64 + qd*16 + j] = (bf16)(e[j]*inv);
}

// ---------- out2[n][d] = sum_e P[d][e] * q[n][e], per (b,g); MFMA ----------
__global__ __launch_bounds__(256) void k_apply(const bf16* __restrict__ qkv, const bf16* __restrict__ P, bf16* __restrict__ outA){
  const int bg = blockIdx.y, b = bg>>4, g = bg&15;
  const int m0 = blockIdx.x*128;
  __shared__ __align__(16) bf16 Pl[64][72];   // pad 64->72 elems (144B rows, 16B-aligned)
  const int t = threadIdx.x, w = t>>6, l = t&63;
  for (int idx=t; idx<1024; idx+=256){
    int r = idx>>4, c4 = (idx&15)*4;
    *(uint2*)&Pl[r][c4] = *(const uint2*)&P[(size_t)bg*4096 + r*64 + c4];
  }
  __syncthreads();
  f32x4 acc[2][4] = {};
  const bf16* qb = qkv + (size_t)(b*4096 + m0 + w*32)*3072 + g*64;
  #pragma unroll
  for (int kk=0; kk<64; kk+=32){
    bf16x8 af[2], pf[4];
    #pragma unroll
    for (int mf=0;mf<2;++mf)
      af[mf] = *(const bf16x8*)(qb + (size_t)(mf*16 + (l&15))*3072 + kk + 8*(l>>4));
    #pragma unroll
    for (int nf=0;nf<4;++nf)
      pf[nf] = *(const bf16x8*)&Pl[nf*16 + (l&15)][kk + 8*(l>>4)];
    #pragma unroll
    for (int mf=0;mf<2;++mf)
      #pragma unroll
      for (int nf=0;nf<4;++nf)
        acc[mf][nf] = __builtin_amdgcn_mfma_f32_16x16x32_bf16(af[mf], pf[nf], acc[mf][nf], 0,0,0);
  }
  #pragma unroll
  for (int mf=0;mf<2;++mf)
    #pragma unroll
    for (int nf=0;nf<4;++nf)
      #pragma unroll
      for (int r=0;r<4;++r){
        int rown = m0 + w*32 + mf*16 + (l>>4)*4 + r;
        int col = g*64 + nf*16 + (l&15);
        outA[(size_t)(b*4096 + rown)*1024 + col] = (bf16)acc[mf][nf][r];
      }
}

// ---------- LayerNorm: wave per row of 1024 ----------
__global__ __launch_bounds__(256) void k_ln(const bf16* __restrict__ h, const float* __restrict__ gamma,
                                            const float* __restrict__ beta, float* __restrict__ y){
  const int w = threadIdx.x>>6, l = threadIdx.x&63;
  const size_t row = (size_t)blockIdx.x*4 + w;
  const bf16* hr = h + row*1024 + l*16;
  uint4 p0 = *(const uint4*)hr;
  uint4 p1 = *(const uint4*)(hr+8);
  float v[16];
  const uint32_t* pw = (const uint32_t*)&p0;
  #pragma unroll
  for (int i=0;i<4;++i){ v[2*i] = bits2f(pw[i]<<16); v[2*i+1] = bits2f(pw[i]&0xffff0000u); }
  const uint32_t* pw1 = (const uint32_t*)&p1;
  #pragma unroll
  for (int i=0;i<4;++i){ v[8+2*i] = bits2f(pw1[i]<<16); v[8+2*i+1] = bits2f(pw1[i]&0xffff0000u); }
  float s=0.f, s2=0.f;
  #pragma unroll
  for (int i=0;i<16;++i){ s+=v[i]; s2+=v[i]*v[i]; }
  #pragma unroll
  for (int off=1; off<64; off<<=1){ s += __shfl_xor(s,off); s2 += __shfl_xor(s2,off); }
  float mu = s*(1.0f/1024.0f);
  float var = s2*(1.0f/1024.0f) - mu*mu;
  float rinv = rsqrtf(var + 1e-5f);
  const float* gp = gamma + l*16; const float* bp = beta + l*16;
  float o[16];
  #pragma unroll
  for (int i=0;i<16;++i) o[i] = gp[i]*(v[i]-mu)*rinv + bp[i];
  float* yr = y + row*1024 + l*16;
  #pragma unroll
  for (int i=0;i<4;++i) ((float4*)yr)[i] = *(float4*)&o[4*i];
}

extern "C" void kernel_launch(void* const* d_in, const int* in_sizes, int n_in,
                              void* d_out, int out_size, void* d_ws, size_t ws_size,
                              hipStream_t stream){
  const float* x     = (const float*)d_in[0];
  const float* Wqkv  = (const float*)d_in[1];
  const float* Wproj = (const float*)d_in[2];
  const float* bproj = (const float*)d_in[3];
  const float* gamma = (const float*)d_in[4];
  const float* beta  = (const float*)d_in[5];
  float* y = (float*)d_out;

  char* ws = (char*)d_ws;
  size_t off = 0;
  auto alloc = [&](size_t bytes)->void*{ void* p = ws + off; off += (bytes + 255) & ~(size_t)255; return p; };
  bf16*  qkv    = (bf16*) alloc((size_t)32768*3072*2);  // 201.3 MB
  bf16*  xb     = (bf16*) alloc((size_t)32768*1024*2);  // 67.1 MB (x_bf16, then out_attn)
  bf16*  WqkvT  = (bf16*) alloc((size_t)3072*1024*2);
  bf16*  WprojT = (bf16*) alloc((size_t)1024*1024*2);
  float* Sp     = (float*)alloc((size_t)8*128*4096*4);  // 16.8 MB
  bf16*  P      = (bf16*) alloc((size_t)128*4096*2);
  bf16*  h      = qkv;  // qkv dead after k_apply; reuse for h

  k_cast<<<16384,256,0,stream>>>(x, xb, 33554432);
  k_transpose<<<dim3(96,32),256,0,stream>>>(Wqkv, WqkvT, 1024, 3072);
  k_transpose<<<dim3(32,32),256,0,stream>>>(Wproj, WprojT, 1024, 1024);
  // qkv = x @ Wqkv   [32768 x 3072]
  k_gemm<0><<<dim3(12,128),512,0,stream>>>(xb, WqkvT, qkv, 32768, 3072, 1024, nullptr, nullptr);
  // S partials (split-K over n)
  k_scores<<<dim3(8,128),256,0,stream>>>(qkv, Sp);
  k_softmax<<<128,256,0,stream>>>(Sp, P);
  // out_attn = q @ P^T  -> xb
  k_apply<<<dim3(32,128),256,0,stream>>>(qkv, P, xb);
  // h = out_attn @ Wproj + bproj + x   [32768 x 1024] bf16
  k_gemm<1><<<dim3(4,128),512,0,stream>>>(xb, WprojT, h, 32768, 1024, 1024, bproj, x);
  k_ln<<<8192,256,0,stream>>>(h, gamma, beta, y);
}

// Round 3
// 525.238 us; speedup vs baseline: 1.0996x; 1.0007x over previous
//
#include <hip/hip_runtime.h>
#include <cstdint>

typedef __bf16 bf16;
typedef __bf16 bf16x8 __attribute__((ext_vector_type(8)));
typedef float f32x4 __attribute__((ext_vector_type(4)));

#define DEVI __device__ __forceinline__

DEVI float bits2f(uint32_t u){ union{uint32_t u;float f;}x; x.u=u; return x.f; }

DEVI void gload_lds16(const void* g, void* l){
  __builtin_amdgcn_global_load_lds(
    (const __attribute__((address_space(1))) uint32_t*)g,
    (__attribute__((address_space(3))) uint32_t*)l, 16, 0, 0);
}

// ---------- cast fp32 -> bf16, 8 elems/thread ----------
__global__ __launch_bounds__(256) void k_cast(const float* __restrict__ x, bf16* __restrict__ o, int n){
  int i = (blockIdx.x*256 + threadIdx.x)*8;
  if (i >= n) return;
  float4 a = *(const float4*)(x+i);
  float4 b = *(const float4*)(x+i+4);
  union { bf16 h[8]; uint4 u; } r;
  r.h[0]=(bf16)a.x; r.h[1]=(bf16)a.y; r.h[2]=(bf16)a.z; r.h[3]=(bf16)a.w;
  r.h[4]=(bf16)b.x; r.h[5]=(bf16)b.y; r.h[6]=(bf16)b.z; r.h[7]=(bf16)b.w;
  *(uint4*)(o+i) = r.u;
}

// ---------- transpose + cast: WT[c][r] = W[r][c] ----------
__global__ __launch_bounds__(256) void k_transpose(const float* __restrict__ W, bf16* __restrict__ WT, int R, int Ccols){
  __shared__ float tile[32][33];
  int bc = blockIdx.x*32, br = blockIdx.y*32;
  int lc = threadIdx.x & 31, lr = threadIdx.x >> 5; // lr 0..7
  #pragma unroll
  for (int i=0;i<4;i++){
    int r = lr + i*8;
    tile[r][lc] = W[(size_t)(br+r)*Ccols + bc + lc];
  }
  __syncthreads();
  #pragma unroll
  for (int i=0;i<4;i++){
    int r = lr + i*8;
    WT[(size_t)(bc+r)*R + br + lc] = (bf16)tile[lc][r];
  }
}

// =====================================================================
// 256x256-tile, BK=64, 8-wave (2M x 4N), software-pipelined ds_reads:
// phase P's MFMA consumes fragments read at phase P-1 (compiler emits
// counted lgkmcnt — no explicit drain). Per-wave quadrant rotation
// qc=(P+wn)&3; A staged own-rows so the p3 cross-tile prefetch is
// confirmed by the wave's own vmcnt(4). B staged cooperatively.
// Queue ledger at p3: B(T+1)4 + A(T+1)4 + B(T+2)4 = 12 -> vmcnt(4).
// =====================================================================
template<int EPI>
__global__ __launch_bounds__(512, 2) void k_gemm(
    const bf16* __restrict__ A, const bf16* __restrict__ BT, bf16* __restrict__ C,
    int M, int N, int K,
    const float* __restrict__ bias, const float* __restrict__ resid)
{
  __shared__ __align__(16) bf16 lds[2][2][256*64];   // [slot][0=A,1=B] = 128 KiB
  bf16* bA0 = &lds[0][0][0]; bf16* bB0 = &lds[0][1][0];
  bf16* bA1 = &lds[1][0][0]; bf16* bB1 = &lds[1][1][0];

  const int t = threadIdx.x, w = t>>6, l = t&63;
  const int wm = w>>2, wn = w&3;

  // XCD-aware bijective block swizzle (m204 variant)
  const int nwg = gridDim.x * gridDim.y;
  const int orig = blockIdx.y * gridDim.x + blockIdx.x;
  const int q = nwg >> 3, r = nwg & 7;
  const int xcd = orig & 7, loc = orig >> 3;
  const int swz = (xcd < r ? xcd*(q+1) : r*(q+1) + (xcd-r)*q) + loc;
  const int bx = swz % gridDim.x, by = swz / gridDim.x;
  const int bm = by*256, bn = bx*256;

  // swizzled read column offsets (bytes within a 128B row), kk = 0,1
  const int co0 = (16*(l>>4)) ^ ((l&7)<<4);
  const int co1 = (64 + 16*(l>>4)) ^ ((l&7)<<4);

  // A staging: wave stages its OWN 32 rows [wm*128+wn*32, +32), 4 issues of 8 rows.
  auto stageA = [&](const bf16* G, bf16* Ldst, int j, int k0){
    int row = wm*128 + wn*32 + j*8 + (l>>3);
    int col = 8*((l&7) ^ (l>>3));
    gload_lds16(G + (size_t)(bm + row)*K + k0 + col,
                Ldst + (wm*128 + wn*32 + j*8)*64);
  };
  // B staging: cooperative, issue j covers rows j*64 + w*8 .. +8.
  auto stageB = [&](const bf16* G, bf16* Ldst, int j, int k0){
    int row = j*64 + w*8 + (l>>3);
    int col = 8*((l&7) ^ (l>>3));
    gload_lds16(G + (size_t)(bn + row)*K + k0 + col,
                Ldst + (j*64 + w*8)*64);
  };

#define RD_AA(dst, qd, base) {                                                  \
    const int r0 = wm*128 + (qd)*32 + (l&15);                                   \
    dst[0][0] = *(const bf16x8*)((const char*)(base) + (r0   )*128 + co0);      \
    dst[0][1] = *(const bf16x8*)((const char*)(base) + (r0   )*128 + co1);      \
    dst[1][0] = *(const bf16x8*)((const char*)(base) + (r0+16)*128 + co0);      \
    dst[1][1] = *(const bf16x8*)((const char*)(base) + (r0+16)*128 + co1);      \
  }

#define MFMA_Q(P, AA) {                                                         \
    __builtin_amdgcn_s_setprio(1);                                              \
    _Pragma("unroll")                                                           \
    for (int kk=0;kk<2;++kk)                                                    \
      _Pragma("unroll")                                                         \
      for (int i=0;i<2;++i)                                                     \
        _Pragma("unroll")                                                       \
        for (int nf=0;nf<4;++nf)                                                \
          acc[2*(P)+i][nf] = __builtin_amdgcn_mfma_f32_16x16x32_bf16(           \
              AA[i][kk], bfr[nf][kk], acc[2*(P)+i][nf], 0,0,0);                 \
    __builtin_amdgcn_s_setprio(0);                                              \
  }

#define BAR asm volatile("s_barrier" ::: "memory")

  f32x4 acc[8][4] = {};
  const int NT = K >> 6;

  // ---- prologue: stage A(0) own, B(0), B(1) coop; confirm A(0),B(0) ----
  #pragma unroll
  for (int j=0;j<4;++j) stageA(A, bA0, j, 0);
  #pragma unroll
  for (int j=0;j<4;++j) stageB(BT, bB0, j, 0);
  __builtin_amdgcn_sched_barrier(0);
  if (NT > 1){
    #pragma unroll
    for (int j=0;j<4;++j) stageB(BT, bB1, j, 64);
    asm volatile("s_waitcnt vmcnt(4)" ::: "memory");
  } else {
    asm volatile("s_waitcnt vmcnt(0)" ::: "memory");
  }
  BAR;

  bf16x8 aaA[2][2], aaB[2][2];
  RD_AA(aaA, wn, bA0);   // tile-0 first quadrant (own rows, own-staged)

  for (int T = 0; T < NT; ++T){
    bf16* sA  = (T&1) ? bA1 : bA0;
    bf16* sB  = (T&1) ? bB1 : bB0;
    bf16* sAn = (T&1) ? bA0 : bA1;
    const int kA = (T+1)<<6, kB = (T+2)<<6;
    const bool stA = (T+1) < NT, stB = (T+2) < NT;

    // B fragments for the whole K-tile, register-cached (8 x ds_read_b128)
    bf16x8 bfr[4][2];
    const int rb = wn*64 + (l&15);
    #pragma unroll
    for (int nf=0;nf<4;++nf){
      bfr[nf][0] = *(const bf16x8*)((const char*)sB + (rb+nf*16)*128 + co0);
      bfr[nf][1] = *(const bf16x8*)((const char*)sB + (rb+nf*16)*128 + co1);
    }

    // P0: compute quad (wn+0), read quad (wn+1), stage A(T+1) j=0,1
    RD_AA(aaB, (wn+1)&3, sA);
    if (stA){ stageA(A, sAn, 0, kA); stageA(A, sAn, 1, kA); }
    BAR; MFMA_Q(0, aaA); BAR;

    // P1: compute quad (wn+1), read quad (wn+2), stage A(T+1) j=2,3
    RD_AA(aaA, (wn+2)&3, sA);
    if (stA){ stageA(A, sAn, 2, kA); stageA(A, sAn, 3, kA); }
    BAR; MFMA_Q(1, aaB); BAR;

    // P2: compute quad (wn+2), read quad (wn+3), stage B(T+2) j=0,1
    RD_AA(aaB, (wn+3)&3, sA);
    if (stB){ stageB(BT, sB, 0, kB); stageB(BT, sB, 1, kB); }
    BAR; MFMA_Q(2, aaA); BAR;

    // P3: compute quad (wn+3); stage B(T+2) j=2,3; vmcnt; prefetch next tile's
    // quad wn from sAn (own rows, confirmed by own vmcnt).
    if (stB){
      stageB(BT, sB, 2, kB); stageB(BT, sB, 3, kB);
      asm volatile("s_waitcnt vmcnt(4)" ::: "memory");
    } else {
      asm volatile("s_waitcnt vmcnt(0)" ::: "memory");
    }
    if (stA) RD_AA(aaA, wn, sAn);
    BAR; MFMA_Q(3, aaB); BAR;
  }
#undef RD_AA
#undef MFMA_Q
#undef BAR

  // ---- epilogue ----
  #pragma unroll
  for (int P=0; P<4; ++P){
    const int qd = (P+wn)&3;
    #pragma unroll
    for (int i=0;i<2;++i){
      #pragma unroll
      for (int nf=0; nf<4; ++nf){
        #pragma unroll
        for (int r2=0; r2<4; ++r2){
          int row = bm + wm*128 + qd*32 + i*16 + (l>>4)*4 + r2;
          int col = bn + wn*64 + nf*16 + (l&15);
          float v = acc[2*P+i][nf][r2];
          if (EPI==1) v += bias[col] + resid[(size_t)row*N + col];
          C[(size_t)row*N + col] = (bf16)v;
        }
      }
    }
  }
}

// ---------- channel scores: Sp[ks][bg][d][e] = sum_{n in ks-chunk} k[n][d]*v[n][e] ----------
__global__ __launch_bounds__(256) void k_scores(const bf16* __restrict__ qkv, float* __restrict__ Sp){
  const int ks = blockIdx.x, bg = blockIdx.y;
  const int b = bg>>4, g = bg&15;
  __shared__ __align__(16) bf16 kT[64][64];
  __shared__ __align__(16) bf16 vT[64][64];
  const int t = threadIdx.x;
  const int d0 = (t&15)*4, e0 = (t>>4)*4;
  float acc[4][4] = {};
  const bf16* base = qkv + (size_t)(b*4096 + ks*512)*3072 + g*64;
  for (int sub=0; sub<8; ++sub){
    __syncthreads();
    for (int idx=t; idx<512; idx+=256){
      int row = idx>>3, c8 = (idx&7)*8;
      const bf16* s = base + (size_t)(sub*64+row)*3072 + 1024 + c8;
      *(uint4*)&kT[row][c8] = *(const uint4*)s;
      *(uint4*)&vT[row][c8] = *(const uint4*)(s + 1024);
    }
    __syncthreads();
    #pragma unroll 4
    for (int n=0;n<64;++n){
      uint2 ku = *(const uint2*)&kT[n][d0];
      uint2 vu = *(const uint2*)&vT[n][e0];
      float kf[4] = { bits2f(ku.x<<16), bits2f(ku.x&0xffff0000u), bits2f(ku.y<<16), bits2f(ku.y&0xffff0000u) };
      float vf[4] = { bits2f(vu.x<<16), bits2f(vu.x&0xffff0000u), bits2f(vu.y<<16), bits2f(vu.y&0xffff0000u) };
      #pragma unroll
      for (int i=0;i<4;++i)
        #pragma unroll
        for (int j=0;j<4;++j)
          acc[i][j] += kf[i]*vf[j];
    }
  }
  float* o = Sp + ((size_t)ks*128 + bg)*4096;
  #pragma unroll
  for (int i=0;i<4;++i)
    #pragma unroll
    for (int j=0;j<4;++j)
      o[(d0+i)*64 + e0+j] = acc[i][j];
}

// ---------- reduce partials, scale, softmax over e, write bf16 P ----------
__global__ __launch_bounds__(256) void k_softmax(const float* __restrict__ Sp, bf16* __restrict__ P){
  const int bg = blockIdx.x;
  __shared__ float S[64][64];
  const int t = threadIdx.x;
  for (int idx=t; idx<4096; idx+=256){
    float s = 0;
    #pragma unroll
    for (int ks=0;ks<8;++ks) s += Sp[((size_t)ks*128+bg)*4096 + idx];
    S[idx>>6][idx&63] = s * 0.125f;  // scale = hd^-0.5
  }
  __syncthreads();
  const int row = t>>2, qd = t&3;
  float m = -3.4e38f;
  #pragma unroll
  for (int j=0;j<16;++j) m = fmaxf(m, S[row][qd*16+j]);
  m = fmaxf(m, __shfl_xor(m,1));
  m = fmaxf(m, __shfl_xor(m,2));
  float e[16]; float sum = 0.f;
  #pragma unroll
  for (int j=0;j<16;++j){ e[j] = expf(S[row][qd*16+j]-m); sum += e[j]; }
  sum += __shfl_xor(sum,1);
  sum += __shfl_xor(sum,2);
  float inv = 1.0f/sum;
  #pragma unroll
  for (int j=0;j<16;++j) P[(size_t)bg*4096 + row*64 + qd*16 + j] = (bf16)(e[j]*inv);
}

// ---------- out2[n][d] = sum_e P[d][e] * q[n][e], per (b,g); MFMA ----------
__global__ __launch_bounds__(256) void k_apply(const bf16* __restrict__ qkv, const bf16* __restrict__ P, bf16* __restrict__ outA){
  const int bg = blockIdx.y, b = bg>>4, g = bg&15;
  const int m0 = blockIdx.x*128;
  __shared__ __align__(16) bf16 Pl[64][72];   // pad 64->72 elems (144B rows, 16B-aligned)
  const int t = threadIdx.x, w = t>>6, l = t&63;
  for (int idx=t; idx<1024; idx+=256){
    int r = idx>>4, c4 = (idx&15)*4;
    *(uint2*)&Pl[r][c4] = *(const uint2*)&P[(size_t)bg*4096 + r*64 + c4];
  }
  __syncthreads();
  f32x4 acc[2][4] = {};
  const bf16* qb = qkv + (size_t)(b*4096 + m0 + w*32)*3072 + g*64;
  #pragma unroll
  for (int kk=0; kk<64; kk+=32){
    bf16x8 af[2], pf[4];
    #pragma unroll
    for (int mf=0;mf<2;++mf)
      af[mf] = *(const bf16x8*)(qb + (size_t)(mf*16 + (l&15))*3072 + kk + 8*(l>>4));
    #pragma unroll
    for (int nf=0;nf<4;++nf)
      pf[nf] = *(const bf16x8*)&Pl[nf*16 + (l&15)][kk + 8*(l>>4)];
    #pragma unroll
    for (int mf=0;mf<2;++mf)
      #pragma unroll
      for (int nf=0;nf<4;++nf)
        acc[mf][nf] = __builtin_amdgcn_mfma_f32_16x16x32_bf16(af[mf], pf[nf], acc[mf][nf], 0,0,0);
  }
  #pragma unroll
  for (int mf=0;mf<2;++mf)
    #pragma unroll
    for (int nf=0;nf<4;++nf)
      #pragma unroll
      for (int r=0;r<4;++r){
        int rown = m0 + w*32 + mf*16 + (l>>4)*4 + r;
        int col = g*64 + nf*16 + (l&15);
        outA[(size_t)(b*4096 + rown)*1024 + col] = (bf16)acc[mf][nf][r];
      }
}

// ---------- LayerNorm: wave per row of 1024 ----------
__global__ __launch_bounds__(256) void k_ln(const bf16* __restrict__ h, const float* __restrict__ gamma,
                                            const float* __restrict__ beta, float* __restrict__ y){
  const int w = threadIdx.x>>6, l = threadIdx.x&63;
  const size_t row = (size_t)blockIdx.x*4 + w;
  const bf16* hr = h + row*1024 + l*16;
  uint4 p0 = *(const uint4*)hr;
  uint4 p1 = *(const uint4*)(hr+8);
  float v[16];
  const uint32_t* pw = (const uint32_t*)&p0;
  #pragma unroll
  for (int i=0;i<4;++i){ v[2*i] = bits2f(pw[i]<<16); v[2*i+1] = bits2f(pw[i]&0xffff0000u); }
  const uint32_t* pw1 = (const uint32_t*)&p1;
  #pragma unroll
  for (int i=0;i<4;++i){ v[8+2*i] = bits2f(pw1[i]<<16); v[8+2*i+1] = bits2f(pw1[i]&0xffff0000u); }
  float s=0.f, s2=0.f;
  #pragma unroll
  for (int i=0;i<16;++i){ s+=v[i]; s2+=v[i]*v[i]; }
  #pragma unroll
  for (int off=1; off<64; off<<=1){ s += __shfl_xor(s,off); s2 += __shfl_xor(s2,off); }
  float mu = s*(1.0f/1024.0f);
  float var = s2*(1.0f/1024.0f) - mu*mu;
  float rinv = rsqrtf(var + 1e-5f);
  const float* gp = gamma + l*16; const float* bp = beta + l*16;
  float o[16];
  #pragma unroll
  for (int i=0;i<16;++i) o[i] = gp[i]*(v[i]-mu)*rinv + bp[i];
  float* yr = y + row*1024 + l*16;
  #pragma unroll
  for (int i=0;i<4;++i) ((float4*)yr)[i] = *(float4*)&o[4*i];
}

extern "C" void kernel_launch(void* const* d_in, const int* in_sizes, int n_in,
                              void* d_out, int out_size, void* d_ws, size_t ws_size,
                              hipStream_t stream){
  const float* x     = (const float*)d_in[0];
  const float* Wqkv  = (const float*)d_in[1];
  const float* Wproj = (const float*)d_in[2];
  const float* bproj = (const float*)d_in[3];
  const float* gamma = (const float*)d_in[4];
  const float* beta  = (const float*)d_in[5];
  float* y = (float*)d_out;

  char* ws = (char*)d_ws;
  size_t off = 0;
  auto alloc = [&](size_t bytes)->void*{ void* p = ws + off; off += (bytes + 255) & ~(size_t)255; return p; };
  bf16*  qkv    = (bf16*) alloc((size_t)32768*3072*2);  // 201.3 MB
  bf16*  xb     = (bf16*) alloc((size_t)32768*1024*2);  // 67.1 MB (x_bf16, then out_attn)
  bf16*  WqkvT  = (bf16*) alloc((size_t)3072*1024*2);
  bf16*  WprojT = (bf16*) alloc((size_t)1024*1024*2);
  float* Sp     = (float*)alloc((size_t)8*128*4096*4);  // 16.8 MB
  bf16*  P      = (bf16*) alloc((size_t)128*4096*2);
  bf16*  h      = qkv;  // qkv dead after k_apply; reuse for h

  k_cast<<<16384,256,0,stream>>>(x, xb, 33554432);
  k_transpose<<<dim3(96,32),256,0,stream>>>(Wqkv, WqkvT, 1024, 3072);
  k_transpose<<<dim3(32,32),256,0,stream>>>(Wproj, WprojT, 1024, 1024);
  // qkv = x @ Wqkv   [32768 x 3072]
  k_gemm<0><<<dim3(12,128),512,0,stream>>>(xb, WqkvT, qkv, 32768, 3072, 1024, nullptr, nullptr);
  // S partials (split-K over n)
  k_scores<<<dim3(8,128),256,0,stream>>>(qkv, Sp);
  k_softmax<<<128,256,0,stream>>>(Sp, P);
  // out_attn = q @ P^T  -> xb
  k_apply<<<dim3(32,128),256,0,stream>>>(qkv, P, xb);
  // h = out_attn @ Wproj + bproj + x   [32768 x 1024] bf16
  k_gemm<1><<<dim3(4,128),512,0,stream>>>(xb, WprojT, h, 32768, 1024, 1024, bproj, x);
  k_ln<<<8192,256,0,stream>>>(h, gamma, beta, y);
}